// Round 1
// baseline (5183.567 us; speedup 1.0000x reference)
//
#include <hip/hip_runtime.h>

// ---------------------------------------------------------------------------
// Shapes / constants
// ---------------------------------------------------------------------------
constexpr int Bn  = 128;
constexpr int H0  = 98, Wi0 = 40;
constexpr int KH1 = 20, KW1 = 8, H1 = 79, Wo1 = 33, P1 = H1 * Wo1;   // 2607
constexpr int KH2 = 15, KW2 = 8, H2 = 65, Wo2 = 26, P2 = H2 * Wo2;   // 1690
constexpr int KH3 = 10, KW3 = 8, H3 = 56, Wo3 = 19, P3 = H3 * Wo3;   // 1064
constexpr int M1  = Bn * P1;   // 333696
constexpr int M2  = Bn * P2;   // 216320 = 845*256
constexpr int M3  = Bn * P3;   // 136192 = 532*256
constexpr int KFC = 64 * P3;   // 68096
constexpr int FCCH = 128;           // fc1 split-K chunks
constexpr int FCKL = KFC / FCCH;    // 532

// ---------------------------------------------------------------------------
// Workspace layout (floats)
// ---------------------------------------------------------------------------
constexpr size_t oA  = 0;                                   // ping buffer (max 21,356,544)
constexpr size_t oB  = oA  + (size_t)Bn * 64 * P1;          // pong buffer (max 20,689,152)
constexpr size_t oW2 = oB  + (size_t)Bn * 62 * P1;          // prepped W21 (491,520)
constexpr size_t oW3 = oW2 + (size_t)64 * 64 * KH2 * KW2;   // prepped W31 (327,680)
constexpr size_t oP  = oW3 + (size_t)64 * 64 * KH3 * KW3;   // fc1 partials (128*8192)
constexpr size_t oSt = oP  + (size_t)FCCH * 8192;           // stats: 9 slots x 128
constexpr size_t oAf = oSt + 9 * 128;                       // affine: 9 slots x 128
constexpr size_t oB2 = oAf + 9 * 128;                       // prepped bias2 (64)
constexpr size_t oB3 = oB2 + 64;                            // prepped bias3 (64)
constexpr size_t oF  = oB3 + 64;                            // fc1 out (128x64)
constexpr size_t oFA = oF  + 8192;                          // fc affine (128)
constexpr size_t WS_FLOATS = oFA + 128;                     // ~43.9M floats ~176MB

// ---------------------------------------------------------------------------
// Reduction helpers
// ---------------------------------------------------------------------------
__device__ __forceinline__ float wred(float v) {
    #pragma unroll
    for (int o = 32; o > 0; o >>= 1) v += __shfl_down(v, o);
    return v;
}

// ---------------------------------------------------------------------------
// conv1: (128,1,98,40) -> (128,64,79,33), + b11
// thread = one spatial position, 8 output channels (blockIdx.y)
// ---------------------------------------------------------------------------
__global__ __launch_bounds__(256) void k_conv1(const float* __restrict__ x,
                                               const float* __restrict__ w,
                                               const float* __restrict__ bias,
                                               float* __restrict__ out) {
    int m = blockIdx.x * 256 + threadIdx.x;
    if (m >= M1) m = M1 - 1;                    // clamp (duplicate writes benign)
    const int oc0 = blockIdx.y * 8;
    int b = m / P1; int r = m - b * P1;
    int oh = r / Wo1; int ow = r - oh * Wo1;
    const float* xp = x + (size_t)(b * H0 + oh) * Wi0 + ow;
    float acc[8] = {0, 0, 0, 0, 0, 0, 0, 0};
    for (int kh = 0; kh < KH1; ++kh) {
        const float* xr = xp + kh * Wi0;
        const float* wr = w + (size_t)oc0 * (KH1 * KW1) + kh * KW1;
        #pragma unroll
        for (int kw = 0; kw < KW1; ++kw) {
            float v = xr[kw];
            #pragma unroll
            for (int j = 0; j < 8; ++j)
                acc[j] += v * wr[(size_t)j * (KH1 * KW1) + kw];
        }
    }
    #pragma unroll
    for (int j = 0; j < 8; ++j)
        out[(size_t)(b * 64 + oc0 + j) * P1 + r] = acc[j] + bias[oc0 + j];
}

// ---------------------------------------------------------------------------
// generic 64->64 conv with pre-scaled weights (+ bias)
// ---------------------------------------------------------------------------
template <int KH, int KW, int IH, int IW, int OH, int OW>
__global__ __launch_bounds__(256) void k_conv64(const float* __restrict__ in,
                                                const float* __restrict__ w,
                                                const float* __restrict__ bias,
                                                float* __restrict__ out) {
    constexpr int PIN = IH * IW, POUT = OH * OW, KK = KH * KW;
    int m = blockIdx.x * 256 + threadIdx.x;     // exact multiple of 256
    const int oc0 = blockIdx.y * 8;
    int b = m / POUT; int r = m - b * POUT;
    int oh = r / OW; int ow = r - oh * OW;
    const float* ip = in + (size_t)b * 64 * PIN + oh * IW + ow;
    float acc[8] = {0, 0, 0, 0, 0, 0, 0, 0};
    for (int ic = 0; ic < 64; ++ic) {
        const float* icp = ip + (size_t)ic * PIN;
        const float* wp  = w + ((size_t)oc0 * 64 + ic) * KK;
        for (int kh = 0; kh < KH; ++kh) {
            const float* xr = icp + kh * IW;
            const float* wr = wp + kh * KW;
            #pragma unroll
            for (int kw = 0; kw < KW; ++kw) {
                float v = xr[kw];
                #pragma unroll
                for (int j = 0; j < 8; ++j)
                    acc[j] += v * wr[(size_t)j * 64 * KK + kw];
            }
        }
    }
    #pragma unroll
    for (int j = 0; j < 8; ++j)
        out[(size_t)(b * 64 + oc0 + j) * POUT + r] = acc[j] + bias[oc0 + j];
}

// ---------------------------------------------------------------------------
// per-channel stats (64-channel buffers): sum -> stats[c], sumsq -> stats[64+c]
// ---------------------------------------------------------------------------
template <int POS>
__global__ __launch_bounds__(256) void k_stats_ch(const float* __restrict__ buf,
                                                  float* __restrict__ stats) {
    const int c = blockIdx.y;
    float s = 0.f, ss = 0.f;
    for (int i = blockIdx.x * 256 + threadIdx.x; i < Bn * POS; i += gridDim.x * 256) {
        int b = i / POS; int p = i - b * POS;
        float v = buf[(size_t)(b * 64 + c) * POS + p];
        s += v; ss += v * v;
    }
    s = wred(s); ss = wred(ss);
    __shared__ float ls[4], lss[4];
    int wv = threadIdx.x >> 6, ln = threadIdx.x & 63;
    if (ln == 0) { ls[wv] = s; lss[wv] = ss; }
    __syncthreads();
    if (threadIdx.x == 0) {
        atomicAdd(&stats[c],      ls[0] + ls[1] + ls[2] + ls[3]);
        atomicAdd(&stats[64 + c], lss[0] + lss[1] + lss[2] + lss[3]);
    }
}

// global stats over N contiguous elements
template <int N>
__global__ __launch_bounds__(256) void k_stats_all(const float* __restrict__ buf,
                                                   float* __restrict__ stats) {
    float s = 0.f, ss = 0.f;
    for (int i = blockIdx.x * 256 + threadIdx.x; i < N; i += gridDim.x * 256) {
        float v = buf[i];
        s += v; ss += v * v;
    }
    s = wred(s); ss = wred(ss);
    __shared__ float ls[4], lss[4];
    int wv = threadIdx.x >> 6, ln = threadIdx.x & 63;
    if (ln == 0) { ls[wv] = s; lss[wv] = ss; }
    __syncthreads();
    if (threadIdx.x == 0) {
        atomicAdd(&stats[0],  ls[0] + ls[1] + ls[2] + ls[3]);
        atomicAdd(&stats[64], lss[0] + lss[1] + lss[2] + lss[3]);
    }
}

// stats -> (scale, shift):  y = scale*x + shift  ==  (x-m)*rsqrt(v+eps)*g + be
__global__ void k_affine(const float* __restrict__ stats, const float* __restrict__ g,
                         const float* __restrict__ be, float* __restrict__ aff,
                         int C, float invCount) {
    int t = threadIdx.x;
    if (t < C) {
        float m  = stats[t] * invCount;
        float v  = stats[64 + t] * invCount - m * m;
        float sc = g[t] * rsqrtf(v + 1e-5f);
        aff[t] = sc;
        aff[64 + t] = be[t] - m * sc;
    }
}

// ---------------------------------------------------------------------------
// lc: in 64ch (pre-BN), apply affine+relu on load, 3-tap channel conv -> 62ch
// ---------------------------------------------------------------------------
template <int POS>
__global__ __launch_bounds__(256) void k_lc(const float* __restrict__ in,
                                            const float* __restrict__ aff,
                                            const float* __restrict__ lcw,
                                            const float* __restrict__ lcb,
                                            float* __restrict__ out) {
    int m = blockIdx.x * 256 + threadIdx.x;
    if (m >= Bn * POS) m = Bn * POS - 1;
    int b = m / POS; int p = m - b * POS;
    const float* ip = in + (size_t)b * 64 * POS + p;
    float* op = out + (size_t)b * 62 * POS + p;
    float y0 = fmaxf(aff[0] * ip[0]            + aff[64], 0.f);
    float y1 = fmaxf(aff[1] * ip[(size_t)POS]  + aff[65], 0.f);
    for (int c = 0; c < 62; ++c) {
        float y2 = fmaxf(aff[c + 2] * ip[(size_t)(c + 2) * POS] + aff[64 + c + 2], 0.f);
        op[(size_t)c * POS] = lcb[c] + y0 * lcw[c * 3] + y1 * lcw[c * 3 + 1] + y2 * lcw[c * 3 + 2];
        y0 = y1; y1 = y2;
    }
}

// ---------------------------------------------------------------------------
// mix: in 62ch (pre-bn_all), apply scalar affine+relu, channel-mix to 64, +bm
// ---------------------------------------------------------------------------
template <int POS>
__global__ __launch_bounds__(256) void k_mix(const float* __restrict__ in,
                                             const float* __restrict__ aff,
                                             const float* __restrict__ Wm,
                                             const float* __restrict__ bm,
                                             float* __restrict__ out) {
    int m = blockIdx.x * 256 + threadIdx.x;
    if (m >= Bn * POS) m = Bn * POS - 1;
    int b = m / POS; int p = m - b * POS;
    const float s0 = aff[0], t0 = aff[64];
    const float* ip = in + (size_t)b * 62 * POS + p;
    float z[62];
    #pragma unroll
    for (int d = 0; d < 62; ++d)
        z[d] = fmaxf(s0 * ip[(size_t)d * POS] + t0, 0.f);
    float* op = out + (size_t)b * 64 * POS + p;
    for (int c = 0; c < 64; ++c) {
        float acc = bm[c];
        #pragma unroll
        for (int d = 0; d < 62; ++d) acc += z[d] * Wm[c * 62 + d];
        op[(size_t)c * POS] = acc;
    }
}

// ---------------------------------------------------------------------------
// fold per-input-channel affine into conv weights: W' = W*scale[ic],
// bias' = bias[oc] + sum(W*shift[ic])
// ---------------------------------------------------------------------------
template <int KK>
__global__ __launch_bounds__(256) void k_prepw(const float* __restrict__ w,
                                               const float* __restrict__ aff,
                                               const float* __restrict__ bias,
                                               float* __restrict__ wp,
                                               float* __restrict__ biasp) {
    int oc = blockIdx.x;
    float local = 0.f;
    for (int i = threadIdx.x; i < 64 * KK; i += 256) {
        int ic = i / KK;
        float wv = w[(size_t)oc * 64 * KK + i];
        wp[(size_t)oc * 64 * KK + i] = wv * aff[ic];
        local += wv * aff[64 + ic];
    }
    local = wred(local);
    __shared__ float ls[4];
    int wv2 = threadIdx.x >> 6, ln = threadIdx.x & 63;
    if (ln == 0) ls[wv2] = local;
    __syncthreads();
    if (threadIdx.x == 0) biasp[oc] = bias[oc] + ls[0] + ls[1] + ls[2] + ls[3];
}

// ---------------------------------------------------------------------------
// fused bn-affine + transpose: A[b][j] (j=c*P3+p) -> hT[j][b]
// ---------------------------------------------------------------------------
__global__ __launch_bounds__(256) void k_transpose(const float* __restrict__ in,
                                                   const float* __restrict__ aff,
                                                   float* __restrict__ hT) {
    __shared__ float tile[32][33];
    int j0 = blockIdx.x * 32, b0 = blockIdx.y * 32;
    int lo = threadIdx.x & 31, hi = threadIdx.x >> 5;   // hi: 0..7
    #pragma unroll
    for (int t = 0; t < 4; ++t) {
        int bl = t * 8 + hi;
        int j  = j0 + lo;
        int c  = j / P3;
        tile[bl][lo] = aff[c] * in[(size_t)(b0 + bl) * KFC + j] + aff[64 + c];
    }
    __syncthreads();
    #pragma unroll
    for (int t = 0; t < 4; ++t) {
        int jl = t * 8 + hi;
        hT[(size_t)(j0 + jl) * Bn + b0 + lo] = tile[lo][jl];
    }
}

// ---------------------------------------------------------------------------
// fc1 split-K: wave = 64 batch lanes x 16 features; partials -> Pb[kc][b][f]
// ---------------------------------------------------------------------------
__global__ __launch_bounds__(256) void k_fc1(const float* __restrict__ hT,
                                             const float* __restrict__ Wf1,
                                             float* __restrict__ Pb) {
    int lane = threadIdx.x & 63;
    int f0 = __builtin_amdgcn_readfirstlane((threadIdx.x >> 6) * 16);
    int b  = blockIdx.y * 64 + lane;
    int kc = blockIdx.x;
    int k0 = kc * FCKL;
    float acc[16] = {};
    for (int k = k0; k < k0 + FCKL; ++k) {
        float hv = hT[(size_t)k * Bn + b];
        #pragma unroll
        for (int f = 0; f < 16; ++f)
            acc[f] += hv * Wf1[(size_t)(f0 + f) * KFC + k];
    }
    float* pp = Pb + (size_t)kc * 8192 + (size_t)b * 64 + f0;
    #pragma unroll
    for (int f = 0; f < 16; ++f) pp[f] = acc[f];
}

__global__ __launch_bounds__(256) void k_fc1red(const float* __restrict__ Pb,
                                                float* __restrict__ F) {
    int m = blockIdx.x * 256 + threadIdx.x;   // 8192
    float s = 0.f;
    for (int kc = 0; kc < FCCH; ++kc) s += Pb[(size_t)kc * 8192 + m];
    F[m] = s;
}

// batch-BN stats over 128 samples per feature (+bf1), -> scale/shift
__global__ void k_fcstats(const float* __restrict__ F, const float* __restrict__ bf1,
                          const float* __restrict__ gf, const float* __restrict__ bef,
                          float* __restrict__ fa) {
    int f = threadIdx.x;   // 64
    float s = 0.f, ss = 0.f;
    for (int b = 0; b < Bn; ++b) {
        float v = F[b * 64 + f] + bf1[f];
        s += v; ss += v * v;
    }
    float m  = s / 128.f;
    float va = ss / 128.f - m * m;
    float sc = gf[f] * rsqrtf(va + 1e-5f);
    fa[f] = sc;
    fa[64 + f] = bef[f] - m * sc;
}

__global__ __launch_bounds__(256) void k_fc2(const float* __restrict__ F,
                                             const float* __restrict__ bf1,
                                             const float* __restrict__ fa,
                                             const float* __restrict__ Wf2,
                                             const float* __restrict__ bf2,
                                             float* __restrict__ out) {
    int m = blockIdx.x * 256 + threadIdx.x;
    if (m >= Bn * 35) return;
    int b = m / 35, o = m - b * 35;
    float acc = bf2[o];
    for (int f = 0; f < 64; ++f) {
        float v = F[b * 64 + f] + bf1[f];
        float z = fmaxf(fa[f] * v + fa[64 + f], 0.f);
        acc += z * Wf2[o * 64 + f];
    }
    out[m] = acc;
}

// ---------------------------------------------------------------------------
// launch
// ---------------------------------------------------------------------------
extern "C" void kernel_launch(void* const* d_in, const int* in_sizes, int n_in,
                              void* d_out, int out_size, void* d_ws, size_t ws_size,
                              hipStream_t stream) {
    const float* x    = (const float*)d_in[0];
    const float* W11  = (const float*)d_in[1];
    const float* b11  = (const float*)d_in[2];
    const float* g11  = (const float*)d_in[3];
    const float* be11 = (const float*)d_in[4];
    const float* lc1w = (const float*)d_in[5];
    const float* lc1b = (const float*)d_in[6];
    const float* g12  = (const float*)d_in[7];
    const float* be12 = (const float*)d_in[8];
    const float* W13  = (const float*)d_in[9];
    const float* b13  = (const float*)d_in[10];
    const float* g13  = (const float*)d_in[11];
    const float* be13 = (const float*)d_in[12];
    const float* W21  = (const float*)d_in[13];
    const float* b21  = (const float*)d_in[14];
    const float* g21  = (const float*)d_in[15];
    const float* be21 = (const float*)d_in[16];
    const float* lc2w = (const float*)d_in[17];
    const float* lc2b = (const float*)d_in[18];
    const float* g22  = (const float*)d_in[19];
    const float* be22 = (const float*)d_in[20];
    const float* W23  = (const float*)d_in[21];
    const float* b23  = (const float*)d_in[22];
    const float* g23  = (const float*)d_in[23];
    const float* be23 = (const float*)d_in[24];
    const float* W31  = (const float*)d_in[25];
    const float* b31  = (const float*)d_in[26];
    const float* g31  = (const float*)d_in[27];
    const float* be31 = (const float*)d_in[28];
    const float* lc3w = (const float*)d_in[29];
    const float* lc3b = (const float*)d_in[30];
    const float* g32  = (const float*)d_in[31];
    const float* be32 = (const float*)d_in[32];
    const float* W33  = (const float*)d_in[33];
    const float* b33  = (const float*)d_in[34];
    const float* g33  = (const float*)d_in[35];
    const float* be33 = (const float*)d_in[36];
    const float* Wf1  = (const float*)d_in[37];
    const float* bf1  = (const float*)d_in[38];
    const float* gf   = (const float*)d_in[39];
    const float* bef  = (const float*)d_in[40];
    const float* Wf2  = (const float*)d_in[41];
    const float* bf2  = (const float*)d_in[42];

    float* ws = (float*)d_ws;
    float* A   = ws + oA;
    float* Bb  = ws + oB;
    float* W2p = ws + oW2;
    float* W3p = ws + oW3;
    float* Pb  = ws + oP;
    float* st  = ws + oSt;   // 9 slots x 128
    float* af  = ws + oAf;   // 9 slots x 128
    float* b2p = ws + oB2;
    float* b3p = ws + oB3;
    float* F   = ws + oF;
    float* fca = ws + oFA;

    // zero the stats accumulators (ws is poisoned each call)
    hipMemsetAsync(st, 0, 9 * 128 * sizeof(float), stream);

    const int blk1 = (M1 + 255) / 256;  // 1304
    const int blk2 = M2 / 256;          // 845
    const int blk3 = M3 / 256;          // 532

    // ---- stage 1 ----
    k_conv1<<<dim3(blk1, 8), 256, 0, stream>>>(x, W11, b11, A);
    k_stats_ch<P1><<<dim3(32, 64), 256, 0, stream>>>(A, st + 0 * 128);
    k_affine<<<1, 64, 0, stream>>>(st + 0 * 128, g11, be11, af + 0 * 128, 64, 1.0f / (float)M1);
    k_lc<P1><<<blk1, 256, 0, stream>>>(A, af + 0 * 128, lc1w, lc1b, Bb);
    k_stats_all<62 * M1><<<512, 256, 0, stream>>>(Bb, st + 1 * 128);
    k_affine<<<1, 64, 0, stream>>>(st + 1 * 128, g12, be12, af + 1 * 128, 1, 1.0f / (62.0f * (float)M1));
    k_mix<P1><<<blk1, 256, 0, stream>>>(Bb, af + 1 * 128, W13, b13, A);
    k_stats_ch<P1><<<dim3(32, 64), 256, 0, stream>>>(A, st + 2 * 128);
    k_affine<<<1, 64, 0, stream>>>(st + 2 * 128, g13, be13, af + 2 * 128, 64, 1.0f / (float)M1);

    // ---- stage 2 ----
    k_prepw<KH2 * KW2><<<64, 256, 0, stream>>>(W21, af + 2 * 128, b21, W2p, b2p);
    k_conv64<KH2, KW2, H1, Wo1, H2, Wo2><<<dim3(blk2, 8), 256, 0, stream>>>(A, W2p, b2p, Bb);
    k_stats_ch<P2><<<dim3(32, 64), 256, 0, stream>>>(Bb, st + 3 * 128);
    k_affine<<<1, 64, 0, stream>>>(st + 3 * 128, g21, be21, af + 3 * 128, 64, 1.0f / (float)M2);
    k_lc<P2><<<blk2, 256, 0, stream>>>(Bb, af + 3 * 128, lc2w, lc2b, A);
    k_stats_all<62 * M2><<<512, 256, 0, stream>>>(A, st + 4 * 128);
    k_affine<<<1, 64, 0, stream>>>(st + 4 * 128, g22, be22, af + 4 * 128, 1, 1.0f / (62.0f * (float)M2));
    k_mix<P2><<<blk2, 256, 0, stream>>>(A, af + 4 * 128, W23, b23, Bb);
    k_stats_ch<P2><<<dim3(32, 64), 256, 0, stream>>>(Bb, st + 5 * 128);
    k_affine<<<1, 64, 0, stream>>>(st + 5 * 128, g23, be23, af + 5 * 128, 64, 1.0f / (float)M2);

    // ---- stage 3 ----
    k_prepw<KH3 * KW3><<<64, 256, 0, stream>>>(W31, af + 5 * 128, b31, W3p, b3p);
    k_conv64<KH3, KW3, H2, Wo2, H3, Wo3><<<dim3(blk3, 8), 256, 0, stream>>>(Bb, W3p, b3p, A);
    k_stats_ch<P3><<<dim3(32, 64), 256, 0, stream>>>(A, st + 6 * 128);
    k_affine<<<1, 64, 0, stream>>>(st + 6 * 128, g31, be31, af + 6 * 128, 64, 1.0f / (float)M3);
    k_lc<P3><<<blk3, 256, 0, stream>>>(A, af + 6 * 128, lc3w, lc3b, Bb);
    k_stats_all<62 * M3><<<512, 256, 0, stream>>>(Bb, st + 7 * 128);
    k_affine<<<1, 64, 0, stream>>>(st + 7 * 128, g32, be32, af + 7 * 128, 1, 1.0f / (62.0f * (float)M3));
    k_mix<P3><<<blk3, 256, 0, stream>>>(Bb, af + 7 * 128, W33, b33, A);
    k_stats_ch<P3><<<dim3(32, 64), 256, 0, stream>>>(A, st + 8 * 128);
    k_affine<<<1, 64, 0, stream>>>(st + 8 * 128, g33, be33, af + 8 * 128, 64, 1.0f / (float)M3);

    // ---- FC head ----
    k_transpose<<<dim3(KFC / 32, Bn / 32), 256, 0, stream>>>(A, af + 8 * 128, Bb);
    k_fc1<<<dim3(FCCH, 2), 256, 0, stream>>>(Bb, Wf1, Pb);
    k_fc1red<<<32, 256, 0, stream>>>(Pb, F);
    k_fcstats<<<1, 64, 0, stream>>>(F, bf1, gf, bef, fca);
    k_fc2<<<(Bn * 35 + 255) / 256, 256, 0, stream>>>(F, bf1, fca, Wf2, bf2, (float*)d_out);
}

// Round 3
// 1506.474 us; speedup vs baseline: 3.4409x; 3.4409x over previous
//
#include <hip/hip_runtime.h>

typedef __bf16 bfrag __attribute__((ext_vector_type(8)));
typedef float ffrag __attribute__((ext_vector_type(16)));

// ---------------------------------------------------------------------------
// Shapes / constants
// ---------------------------------------------------------------------------
constexpr int Bn  = 128;
constexpr int H0  = 98, Wi0 = 40;
constexpr int KH1 = 20, KW1 = 8, H1 = 79, Wo1 = 33, P1 = H1 * Wo1;   // 2607
constexpr int KH2 = 15, KW2 = 8, H2 = 65, Wo2 = 26, P2 = H2 * Wo2;   // 1690
constexpr int KH3 = 10, KW3 = 8, H3 = 56, Wo3 = 19, P3 = H3 * Wo3;   // 1064
constexpr int M1  = Bn * P1;
constexpr int M2  = Bn * P2;
constexpr int M3  = Bn * P3;
constexpr int KFC = 64 * P3;   // 68096
constexpr int FCCH = 128;
constexpr int FCKL = KFC / FCCH;

// ---------------------------------------------------------------------------
// Workspace layout (float slots)
// A: ping fp32. Bb: pong fp32 / bf16 channel-last staging (time-disjoint).
// ---------------------------------------------------------------------------
constexpr size_t oA  = 0;
constexpr size_t oB  = oA  + (size_t)Bn * 64 * P1;          // 21,356,544
constexpr size_t oW2 = oB  + (size_t)Bn * 62 * P1;          // +20,689,152
constexpr size_t oW3 = oW2 + 245760;                        // bf16 wq2 (491,520 el)
constexpr size_t oP  = oW3 + 163840;                        // bf16 wq3 (327,680 el)
constexpr size_t oSt = oP  + (size_t)FCCH * 8192;
constexpr size_t oAf = oSt + 9 * 128;
constexpr size_t oF  = oAf + 9 * 128;
constexpr size_t oFA = oF  + 8192;

__device__ __forceinline__ float wred(float v) {
    #pragma unroll
    for (int o = 32; o > 0; o >>= 1) v += __shfl_down(v, o);
    return v;
}

// ---------------------------------------------------------------------------
// conv1 (fp32 direct, small)
// ---------------------------------------------------------------------------
__global__ __launch_bounds__(256) void k_conv1(const float* __restrict__ x,
                                               const float* __restrict__ w,
                                               const float* __restrict__ bias,
                                               float* __restrict__ out) {
    int m = blockIdx.x * 256 + threadIdx.x;
    if (m >= M1) m = M1 - 1;
    const int oc0 = blockIdx.y * 8;
    int b = m / P1; int r = m - b * P1;
    int oh = r / Wo1; int ow = r - oh * Wo1;
    const float* xp = x + (size_t)(b * H0 + oh) * Wi0 + ow;
    float acc[8] = {0, 0, 0, 0, 0, 0, 0, 0};
    for (int kh = 0; kh < KH1; ++kh) {
        const float* xr = xp + kh * Wi0;
        const float* wr = w + (size_t)oc0 * (KH1 * KW1) + kh * KW1;
        #pragma unroll
        for (int kw = 0; kw < KW1; ++kw) {
            float v = xr[kw];
            #pragma unroll
            for (int j = 0; j < 8; ++j)
                acc[j] += v * wr[(size_t)j * (KH1 * KW1) + kw];
        }
    }
    #pragma unroll
    for (int j = 0; j < 8; ++j)
        out[(size_t)(b * 64 + oc0 + j) * P1 + r] = acc[j] + bias[oc0 + j];
}

// ---------------------------------------------------------------------------
// stats
// ---------------------------------------------------------------------------
template <int POS>
__global__ __launch_bounds__(256) void k_stats_ch(const float* __restrict__ buf,
                                                  float* __restrict__ stats) {
    const int c = blockIdx.y;
    float s = 0.f, ss = 0.f;
    for (int i = blockIdx.x * 256 + threadIdx.x; i < Bn * POS; i += gridDim.x * 256) {
        int b = i / POS; int p = i - b * POS;
        float v = buf[(size_t)(b * 64 + c) * POS + p];
        s += v; ss += v * v;
    }
    s = wred(s); ss = wred(ss);
    __shared__ float ls[4], lss[4];
    int wv = threadIdx.x >> 6, ln = threadIdx.x & 63;
    if (ln == 0) { ls[wv] = s; lss[wv] = ss; }
    __syncthreads();
    if (threadIdx.x == 0) {
        atomicAdd(&stats[c],      ls[0] + ls[1] + ls[2] + ls[3]);
        atomicAdd(&stats[64 + c], lss[0] + lss[1] + lss[2] + lss[3]);
    }
}

template <int N>
__global__ __launch_bounds__(256) void k_stats_all(const float* __restrict__ buf,
                                                   float* __restrict__ stats) {
    float s = 0.f, ss = 0.f;
    for (int i = blockIdx.x * 256 + threadIdx.x; i < N; i += gridDim.x * 256) {
        float v = buf[i];
        s += v; ss += v * v;
    }
    s = wred(s); ss = wred(ss);
    __shared__ float ls[4], lss[4];
    int wv = threadIdx.x >> 6, ln = threadIdx.x & 63;
    if (ln == 0) { ls[wv] = s; lss[wv] = ss; }
    __syncthreads();
    if (threadIdx.x == 0) {
        atomicAdd(&stats[0],  ls[0] + ls[1] + ls[2] + ls[3]);
        atomicAdd(&stats[64], lss[0] + lss[1] + lss[2] + lss[3]);
    }
}

__global__ void k_affine(const float* __restrict__ stats, const float* __restrict__ g,
                         const float* __restrict__ be, float* __restrict__ aff,
                         int C, float invCount) {
    int t = threadIdx.x;
    if (t < C) {
        float m  = stats[t] * invCount;
        float v  = stats[64 + t] * invCount - m * m;
        float sc = g[t] * rsqrtf(v + 1e-5f);
        aff[t] = sc;
        aff[64 + t] = be[t] - m * sc;
    }
}

// ---------------------------------------------------------------------------
// lc / mix
// ---------------------------------------------------------------------------
template <int POS>
__global__ __launch_bounds__(256) void k_lc(const float* __restrict__ in,
                                            const float* __restrict__ aff,
                                            const float* __restrict__ lcw,
                                            const float* __restrict__ lcb,
                                            float* __restrict__ out) {
    int m = blockIdx.x * 256 + threadIdx.x;
    if (m >= Bn * POS) m = Bn * POS - 1;
    int b = m / POS; int p = m - b * POS;
    const float* ip = in + (size_t)b * 64 * POS + p;
    float* op = out + (size_t)b * 62 * POS + p;
    float y0 = fmaxf(aff[0] * ip[0]           + aff[64], 0.f);
    float y1 = fmaxf(aff[1] * ip[(size_t)POS] + aff[65], 0.f);
    for (int c = 0; c < 62; ++c) {
        float y2 = fmaxf(aff[c + 2] * ip[(size_t)(c + 2) * POS] + aff[64 + c + 2], 0.f);
        op[(size_t)c * POS] = lcb[c] + y0 * lcw[c * 3] + y1 * lcw[c * 3 + 1] + y2 * lcw[c * 3 + 2];
        y0 = y1; y1 = y2;
    }
}

template <int POS>
__global__ __launch_bounds__(256) void k_mix(const float* __restrict__ in,
                                             const float* __restrict__ aff,
                                             const float* __restrict__ Wm,
                                             const float* __restrict__ bm,
                                             float* __restrict__ out) {
    int m = blockIdx.x * 256 + threadIdx.x;
    if (m >= Bn * POS) m = Bn * POS - 1;
    int b = m / POS; int p = m - b * POS;
    const float s0 = aff[0], t0 = aff[64];
    const float* ip = in + (size_t)b * 62 * POS + p;
    float z[62];
    #pragma unroll
    for (int d = 0; d < 62; ++d)
        z[d] = fmaxf(s0 * ip[(size_t)d * POS] + t0, 0.f);
    float* op = out + (size_t)b * 64 * POS + p;
    for (int c = 0; c < 64; ++c) {
        float acc = bm[c];
        #pragma unroll
        for (int d = 0; d < 62; ++d) acc += z[d] * Wm[c * 62 + d];
        op[(size_t)c * POS] = acc;
    }
}

// ---------------------------------------------------------------------------
// prep: fp32 [b][64][P] + affine -> bf16 channel-last [(b*IH+ih)*2+half][iw*32+icl]
// ---------------------------------------------------------------------------
template <int IH, int IW>
__global__ __launch_bounds__(256) void k_prep_in(const float* __restrict__ in,
                                                 const float* __restrict__ aff,
                                                 __bf16* __restrict__ out) {
    constexpr int P = IH * IW;
    __shared__ float tile[64][65];
    const int b = blockIdx.y, p0 = blockIdx.x * 64;
    const int pl = threadIdx.x & 63, ch4 = threadIdx.x >> 6;
    #pragma unroll
    for (int i = 0; i < 16; ++i) {
        int c = i * 4 + ch4;
        int p = p0 + pl; if (p > P - 1) p = P - 1;
        tile[pl][c] = in[((size_t)b * 64 + c) * P + p];
    }
    __syncthreads();
    const int cl = threadIdx.x & 63;
    const float sc = aff[cl], sh = aff[64 + cl];
    #pragma unroll
    for (int i = 0; i < 16; ++i) {
        int plocal = i * 4 + ch4;
        int p = p0 + plocal; if (p > P - 1) p = P - 1;
        int ih = p / IW, iw = p - ih * IW;
        float v = sc * tile[plocal][cl] + sh;
        out[(((size_t)b * IH + ih) * 2 + (cl >> 5)) * (IW * 32) + iw * 32 + (cl & 31)] = (__bf16)v;
    }
}

// weights [oc][ic][kh][kw] fp32 -> bf16 packed [pos][c(4)][sub(2)][oc(64)][j(8)]
template <int KH, int KW>
__global__ __launch_bounds__(256) void k_prep_w(const float* __restrict__ w,
                                                __bf16* __restrict__ wq) {
    int idx = blockIdx.x * 256 + threadIdx.x;
    constexpr int TOT = KH * KW * 4096;
    if (idx >= TOT) return;
    int j   = idx & 7;
    int oc  = (idx >> 3) & 63;
    int sub = (idx >> 9) & 1;
    int c   = (idx >> 10) & 3;
    int pos = idx >> 12;
    int kh = pos / KW, kw = pos - kh * KW;
    int ic = c * 16 + sub * 8 + j;
    wq[idx] = (__bf16)w[(((size_t)oc * 64 + ic) * KH + kh) * KW + kw];
}

// ---------------------------------------------------------------------------
// implicit-GEMM conv, 64ch bf16 MFMA 32x32x16
// ---------------------------------------------------------------------------
template <int KH, int KW, int IH, int IW, int OH, int OW, int NR>
__global__ __launch_bounds__(256, 3) void k_convmfma(
    const __bf16* __restrict__ in,   // channel-last halves
    const __bf16* __restrict__ wq,   // packed weights
    const float* __restrict__ bias,
    float* __restrict__ out)         // [b][64][P]
{
    constexpr int P = OH * OW;
    const int b  = blockIdx.y;
    const int m0 = blockIdx.x * 256;
    const int t  = threadIdx.x;
    const int lane = t & 63;
    const int wv = t >> 6;
    const int l31 = lane & 31, lh = lane >> 5;

    __shared__ __align__(16) __bf16 As[NR * IW * 32];

    const int oh_lo = m0 / OW;
    int a_base[2];
    #pragma unroll
    for (int mt = 0; mt < 2; ++mt) {
        int m = m0 + wv * 64 + mt * 32 + l31;
        int mc = m > P - 1 ? P - 1 : m;
        int oh = mc / OW, ow = mc - oh * OW;
        a_base[mt] = ((oh - oh_lo) * IW + ow) * 32 + lh * 8;
    }

    ffrag acc[2][2] = {};

    for (int ich = 0; ich < 2; ++ich) {
        __syncthreads();
        constexpr int ROWCH = IW * 4;          // 16B chunks per row-half
        constexpr int CH = NR * ROWCH;
        for (int idx = t; idx < CH; idx += 256) {
            int r = idx / ROWCH, o = idx - r * ROWCH;
            int ih = oh_lo + r; if (ih > IH - 1) ih = IH - 1;
            const __bf16* src = in + ((size_t)(b * IH + ih) * 2 + ich) * (IW * 32) + o * 8;
            *(uint4*)&As[r * IW * 32 + o * 8] = *(const uint4*)src;
        }
        __syncthreads();

        const __bf16* wich = wq + ich * 2048;
        for (int kh = 0; kh < KH; ++kh) {
            const int arow = kh * IW * 32;
            const __bf16* wkh = wich + (size_t)(kh * KW) * 4096 + lh * 512 + l31 * 8;
            #pragma unroll 2
            for (int kw = 0; kw < KW; ++kw) {
                const __bf16* wp = wkh + kw * 4096;
                #pragma unroll
                for (int cc = 0; cc < 2; ++cc) {
                    const int ao = arow + kw * 32 + cc * 16;
                    bfrag a0 = *(const bfrag*)&As[a_base[0] + ao];
                    bfrag a1 = *(const bfrag*)&As[a_base[1] + ao];
                    bfrag b0 = *(const bfrag*)(wp + cc * 1024);
                    bfrag b1 = *(const bfrag*)(wp + cc * 1024 + 256);
                    acc[0][0] = __builtin_amdgcn_mfma_f32_32x32x16_bf16(a0, b0, acc[0][0], 0, 0, 0);
                    acc[0][1] = __builtin_amdgcn_mfma_f32_32x32x16_bf16(a0, b1, acc[0][1], 0, 0, 0);
                    acc[1][0] = __builtin_amdgcn_mfma_f32_32x32x16_bf16(a1, b0, acc[1][0], 0, 0, 0);
                    acc[1][1] = __builtin_amdgcn_mfma_f32_32x32x16_bf16(a1, b1, acc[1][1], 0, 0, 0);
                }
            }
        }
    }

    // epilogue: C/D col = l31, row = (reg&3) + 8*(reg>>2) + 4*lh
    #pragma unroll
    for (int nt = 0; nt < 2; ++nt) {
        int oc = nt * 32 + l31;
        float bv = bias[oc];
        float* op = out + ((size_t)b * 64 + oc) * P;
        #pragma unroll
        for (int mt = 0; mt < 2; ++mt) {
            int mbase = m0 + wv * 64 + mt * 32 + lh * 4;
            #pragma unroll
            for (int g = 0; g < 4; ++g) {
                int mr = mbase + g * 8;
                if (mr < P) {
                    float2 v01;
                    v01.x = acc[mt][nt][g * 4 + 0] + bv;
                    v01.y = acc[mt][nt][g * 4 + 1] + bv;
                    *(float2*)(op + mr) = v01;
                    if (mr + 2 < P) {
                        float2 v23;
                        v23.x = acc[mt][nt][g * 4 + 2] + bv;
                        v23.y = acc[mt][nt][g * 4 + 3] + bv;
                        *(float2*)(op + mr + 2) = v23;
                    }
                }
            }
        }
    }
}

// ---------------------------------------------------------------------------
// FC head
// ---------------------------------------------------------------------------
__global__ __launch_bounds__(256) void k_transpose(const float* __restrict__ in,
                                                   const float* __restrict__ aff,
                                                   float* __restrict__ hT) {
    __shared__ float tile[32][33];
    int j0 = blockIdx.x * 32, b0 = blockIdx.y * 32;
    int lo = threadIdx.x & 31, hi = threadIdx.x >> 5;
    #pragma unroll
    for (int tt = 0; tt < 4; ++tt) {
        int bl = tt * 8 + hi;
        int j  = j0 + lo;
        int c  = j / P3;
        tile[bl][lo] = aff[c] * in[(size_t)(b0 + bl) * KFC + j] + aff[64 + c];
    }
    __syncthreads();
    #pragma unroll
    for (int tt = 0; tt < 4; ++tt) {
        int jl = tt * 8 + hi;
        hT[(size_t)(j0 + jl) * Bn + b0 + lo] = tile[lo][jl];
    }
}

__global__ __launch_bounds__(256) void k_fc1(const float* __restrict__ hT,
                                             const float* __restrict__ Wf1,
                                             float* __restrict__ Pb) {
    int lane = threadIdx.x & 63;
    int f0 = __builtin_amdgcn_readfirstlane((threadIdx.x >> 6) * 16);
    int b  = blockIdx.y * 64 + lane;
    int kc = blockIdx.x;
    int k0 = kc * FCKL;
    float acc[16] = {};
    for (int k = k0; k < k0 + FCKL; ++k) {
        float hv = hT[(size_t)k * Bn + b];
        #pragma unroll
        for (int f = 0; f < 16; ++f)
            acc[f] += hv * Wf1[(size_t)(f0 + f) * KFC + k];
    }
    float* pp = Pb + (size_t)kc * 8192 + (size_t)b * 64 + f0;
    #pragma unroll
    for (int f = 0; f < 16; ++f) pp[f] = acc[f];
}

__global__ __launch_bounds__(256) void k_fc1red(const float* __restrict__ Pb,
                                                float* __restrict__ F) {
    int m = blockIdx.x * 256 + threadIdx.x;
    float s = 0.f;
    for (int kc = 0; kc < FCCH; ++kc) s += Pb[(size_t)kc * 8192 + m];
    F[m] = s;
}

__global__ void k_fcstats(const float* __restrict__ F, const float* __restrict__ bf1,
                          const float* __restrict__ gf, const float* __restrict__ bef,
                          float* __restrict__ fa) {
    int f = threadIdx.x;
    float s = 0.f, ss = 0.f;
    for (int b = 0; b < Bn; ++b) {
        float v = F[b * 64 + f] + bf1[f];
        s += v; ss += v * v;
    }
    float m  = s / 128.f;
    float va = ss / 128.f - m * m;
    float sc = gf[f] * rsqrtf(va + 1e-5f);
    fa[f] = sc;
    fa[64 + f] = bef[f] - m * sc;
}

__global__ __launch_bounds__(256) void k_fc2(const float* __restrict__ F,
                                             const float* __restrict__ bf1,
                                             const float* __restrict__ fa,
                                             const float* __restrict__ Wf2,
                                             const float* __restrict__ bf2,
                                             float* __restrict__ out) {
    int m = blockIdx.x * 256 + threadIdx.x;
    if (m >= Bn * 35) return;
    int b = m / 35, o = m - b * 35;
    float acc = bf2[o];
    for (int f = 0; f < 64; ++f) {
        float v = F[b * 64 + f] + bf1[f];
        float z = fmaxf(fa[f] * v + fa[64 + f], 0.f);
        acc += z * Wf2[o * 64 + f];
    }
    out[m] = acc;
}

// ---------------------------------------------------------------------------
// launch
// ---------------------------------------------------------------------------
extern "C" void kernel_launch(void* const* d_in, const int* in_sizes, int n_in,
                              void* d_out, int out_size, void* d_ws, size_t ws_size,
                              hipStream_t stream) {
    const float* x    = (const float*)d_in[0];
    const float* W11  = (const float*)d_in[1];
    const float* b11  = (const float*)d_in[2];
    const float* g11  = (const float*)d_in[3];
    const float* be11 = (const float*)d_in[4];
    const float* lc1w = (const float*)d_in[5];
    const float* lc1b = (const float*)d_in[6];
    const float* g12  = (const float*)d_in[7];
    const float* be12 = (const float*)d_in[8];
    const float* W13  = (const float*)d_in[9];
    const float* b13  = (const float*)d_in[10];
    const float* g13  = (const float*)d_in[11];
    const float* be13 = (const float*)d_in[12];
    const float* W21  = (const float*)d_in[13];
    const float* b21  = (const float*)d_in[14];
    const float* g21  = (const float*)d_in[15];
    const float* be21 = (const float*)d_in[16];
    const float* lc2w = (const float*)d_in[17];
    const float* lc2b = (const float*)d_in[18];
    const float* g22  = (const float*)d_in[19];
    const float* be22 = (const float*)d_in[20];
    const float* W23  = (const float*)d_in[21];
    const float* b23  = (const float*)d_in[22];
    const float* g23  = (const float*)d_in[23];
    const float* be23 = (const float*)d_in[24];
    const float* W31  = (const float*)d_in[25];
    const float* b31  = (const float*)d_in[26];
    const float* g31  = (const float*)d_in[27];
    const float* be31 = (const float*)d_in[28];
    const float* lc3w = (const float*)d_in[29];
    const float* lc3b = (const float*)d_in[30];
    const float* g32  = (const float*)d_in[31];
    const float* be32 = (const float*)d_in[32];
    const float* W33  = (const float*)d_in[33];
    const float* b33  = (const float*)d_in[34];
    const float* g33  = (const float*)d_in[35];
    const float* be33 = (const float*)d_in[36];
    const float* Wf1  = (const float*)d_in[37];
    const float* bf1  = (const float*)d_in[38];
    const float* gf   = (const float*)d_in[39];
    const float* bef  = (const float*)d_in[40];
    const float* Wf2  = (const float*)d_in[41];
    const float* bf2  = (const float*)d_in[42];

    float* ws  = (float*)d_ws;
    float* A   = ws + oA;
    float* Bb  = ws + oB;
    __bf16* Bcl = (__bf16*)(ws + oB);   // bf16 view of Bb (time-disjoint use)
    __bf16* wq2 = (__bf16*)(ws + oW2);
    __bf16* wq3 = (__bf16*)(ws + oW3);
    float* Pb  = ws + oP;
    float* st  = ws + oSt;
    float* af  = ws + oAf;
    float* F   = ws + oF;
    float* fca = ws + oFA;

    hipMemsetAsync(st, 0, 9 * 128 * sizeof(float), stream);

    const int blk1 = (M1 + 255) / 256;
    const int blk2 = M2 / 256;
    const int blk3 = M3 / 256;

    // weight packing (independent)
    k_prep_w<KH2, KW2><<<(KH2 * KW2 * 4096 + 255) / 256, 256, 0, stream>>>(W21, wq2);
    k_prep_w<KH3, KW3><<<(KH3 * KW3 * 4096 + 255) / 256, 256, 0, stream>>>(W31, wq3);

    // ---- stage 1 ----
    k_conv1<<<dim3(blk1, 8), 256, 0, stream>>>(x, W11, b11, A);                    // -> A
    k_stats_ch<P1><<<dim3(32, 64), 256, 0, stream>>>(A, st + 0 * 128);
    k_affine<<<1, 64, 0, stream>>>(st + 0 * 128, g11, be11, af + 0 * 128, 64, 1.0f / (float)M1);
    k_lc<P1><<<blk1, 256, 0, stream>>>(A, af + 0 * 128, lc1w, lc1b, Bb);           // A -> Bb
    k_stats_all<62 * M1><<<512, 256, 0, stream>>>(Bb, st + 1 * 128);
    k_affine<<<1, 64, 0, stream>>>(st + 1 * 128, g12, be12, af + 1 * 128, 1, 1.0f / (62.0f * (float)M1));
    k_mix<P1><<<blk1, 256, 0, stream>>>(Bb, af + 1 * 128, W13, b13, A);            // Bb -> A
    k_stats_ch<P1><<<dim3(32, 64), 256, 0, stream>>>(A, st + 2 * 128);
    k_affine<<<1, 64, 0, stream>>>(st + 2 * 128, g13, be13, af + 2 * 128, 64, 1.0f / (float)M1);

    // ---- stage 2 (MFMA conv): A -> Bcl(bf16) -> A ----
    k_prep_in<H1, Wo1><<<dim3((P1 + 63) / 64, Bn), 256, 0, stream>>>(A, af + 2 * 128, Bcl);
    k_convmfma<KH2, KW2, H1, Wo1, H2, Wo2, 25>
        <<<dim3((P2 + 255) / 256, Bn), 256, 0, stream>>>(Bcl, wq2, b21, A);
    k_stats_ch<P2><<<dim3(32, 64), 256, 0, stream>>>(A, st + 3 * 128);
    k_affine<<<1, 64, 0, stream>>>(st + 3 * 128, g21, be21, af + 3 * 128, 64, 1.0f / (float)M2);
    k_lc<P2><<<blk2, 256, 0, stream>>>(A, af + 3 * 128, lc2w, lc2b, Bb);           // A -> Bb
    k_stats_all<62 * M2><<<512, 256, 0, stream>>>(Bb, st + 4 * 128);
    k_affine<<<1, 64, 0, stream>>>(st + 4 * 128, g22, be22, af + 4 * 128, 1, 1.0f / (62.0f * (float)M2));
    k_mix<P2><<<blk2, 256, 0, stream>>>(Bb, af + 4 * 128, W23, b23, A);            // Bb -> A
    k_stats_ch<P2><<<dim3(32, 64), 256, 0, stream>>>(A, st + 5 * 128);
    k_affine<<<1, 64, 0, stream>>>(st + 5 * 128, g23, be23, af + 5 * 128, 64, 1.0f / (float)M2);

    // ---- stage 3 (MFMA conv): A -> Bcl(bf16) -> A ----
    k_prep_in<H2, Wo2><<<dim3((P2 + 63) / 64, Bn), 256, 0, stream>>>(A, af + 5 * 128, Bcl);
    k_convmfma<KH3, KW3, H2, Wo2, H3, Wo3, 24>
        <<<dim3((P3 + 255) / 256, Bn), 256, 0, stream>>>(Bcl, wq3, b31, A);
    k_stats_ch<P3><<<dim3(32, 64), 256, 0, stream>>>(A, st + 6 * 128);
    k_affine<<<1, 64, 0, stream>>>(st + 6 * 128, g31, be31, af + 6 * 128, 64, 1.0f / (float)M3);
    k_lc<P3><<<blk3, 256, 0, stream>>>(A, af + 6 * 128, lc3w, lc3b, Bb);           // A -> Bb
    k_stats_all<62 * M3><<<512, 256, 0, stream>>>(Bb, st + 7 * 128);
    k_affine<<<1, 64, 0, stream>>>(st + 7 * 128, g32, be32, af + 7 * 128, 1, 1.0f / (62.0f * (float)M3));
    k_mix<P3><<<blk3, 256, 0, stream>>>(Bb, af + 7 * 128, W33, b33, A);            // Bb -> A
    k_stats_ch<P3><<<dim3(32, 64), 256, 0, stream>>>(A, st + 8 * 128);
    k_affine<<<1, 64, 0, stream>>>(st + 8 * 128, g33, be33, af + 8 * 128, 64, 1.0f / (float)M3);

    // ---- FC head: A -> Bb(hT) ----
    k_transpose<<<dim3(KFC / 32, Bn / 32), 256, 0, stream>>>(A, af + 8 * 128, Bb);
    k_fc1<<<dim3(FCCH, 2), 256, 0, stream>>>(Bb, Wf1, Pb);
    k_fc1red<<<32, 256, 0, stream>>>(Pb, F);
    k_fcstats<<<1, 64, 0, stream>>>(F, bf1, gf, bef, fca);
    k_fc2<<<(Bn * 35 + 255) / 256, 256, 0, stream>>>(F, bf1, fca, Wf2, bf2, (float*)d_out);
}

// Round 4
// 1304.863 us; speedup vs baseline: 3.9725x; 1.1545x over previous
//
#include <hip/hip_runtime.h>

typedef __bf16 bfrag __attribute__((ext_vector_type(8)));
typedef float ffrag __attribute__((ext_vector_type(16)));

// ---------------------------------------------------------------------------
// Shapes / constants
// ---------------------------------------------------------------------------
constexpr int Bn  = 128;
constexpr int H0  = 98, Wi0 = 40;
constexpr int KH1 = 20, KW1 = 8, H1 = 79, Wo1 = 33, P1 = H1 * Wo1;   // 2607
constexpr int KH2 = 15, KW2 = 8, H2 = 65, Wo2 = 26, P2 = H2 * Wo2;   // 1690
constexpr int KH3 = 10, KW3 = 8, H3 = 56, Wo3 = 19, P3 = H3 * Wo3;   // 1064
constexpr int M1  = Bn * P1;
constexpr int M2  = Bn * P2;
constexpr int M3  = Bn * P3;
constexpr int KFC = 64 * P3;   // 68096
constexpr int FCCH = 128;
constexpr int FCKL = KFC / FCCH;
constexpr float EPSF = 1e-5f;

// ---------------------------------------------------------------------------
// Workspace layout (float slots)
// ---------------------------------------------------------------------------
constexpr size_t oA  = 0;
constexpr size_t oB  = oA  + (size_t)Bn * 64 * P1;          // 21,356,544
constexpr size_t oW2 = oB  + (size_t)Bn * 62 * P1;          // +20,689,152
constexpr size_t oW3 = oW2 + 245760;                        // bf16 wq2
constexpr size_t oP  = oW3 + 163840;                        // bf16 wq3
constexpr size_t oSt = oP  + (size_t)FCCH * 8192;           // stats 9x128
constexpr size_t oF  = oSt + 9 * 128;
constexpr size_t oFA = oF  + 8192;

__device__ __forceinline__ float wred(float v) {
    #pragma unroll
    for (int o = 32; o > 0; o >>= 1) v += __shfl_down(v, o);
    return v;
}
__device__ __forceinline__ float bfly(float v) {
    #pragma unroll
    for (int o = 1; o < 64; o <<= 1) v += __shfl_xor(v, o);
    return v;
}

// ---------------------------------------------------------------------------
// conv1 (fp32 direct) + fused per-channel stats
// ---------------------------------------------------------------------------
__global__ __launch_bounds__(256) void k_conv1(const float* __restrict__ x,
                                               const float* __restrict__ w,
                                               const float* __restrict__ bias,
                                               float* __restrict__ out,
                                               float* __restrict__ sto) {
    int morig = blockIdx.x * 256 + threadIdx.x;
    bool valid = morig < M1;
    int m = valid ? morig : M1 - 1;
    const int oc0 = blockIdx.y * 8;
    int b = m / P1; int r = m - b * P1;
    int oh = r / Wo1; int ow = r - oh * Wo1;
    const float* xp = x + (size_t)(b * H0 + oh) * Wi0 + ow;
    float acc[8] = {0, 0, 0, 0, 0, 0, 0, 0};
    for (int kh = 0; kh < KH1; ++kh) {
        const float* xr = xp + kh * Wi0;
        const float* wr = w + (size_t)oc0 * (KH1 * KW1) + kh * KW1;
        #pragma unroll
        for (int kw = 0; kw < KW1; ++kw) {
            float v = xr[kw];
            #pragma unroll
            for (int j = 0; j < 8; ++j)
                acc[j] += v * wr[(size_t)j * (KH1 * KW1) + kw];
        }
    }
    __shared__ float rs[4][8], rss[4][8];
    int wv = threadIdx.x >> 6, ln = threadIdx.x & 63;
    #pragma unroll
    for (int j = 0; j < 8; ++j) {
        float v = acc[j] + bias[oc0 + j];
        out[(size_t)(b * 64 + oc0 + j) * P1 + r] = v;
        float sv  = wred(valid ? v : 0.f);
        float ssv = wred(valid ? v * v : 0.f);
        if (ln == 0) { rs[wv][j] = sv; rss[wv][j] = ssv; }
    }
    __syncthreads();
    if (threadIdx.x < 8) {
        int j = threadIdx.x;
        atomicAdd(&sto[oc0 + j],      rs[0][j] + rs[1][j] + rs[2][j] + rs[3][j]);
        atomicAdd(&sto[64 + oc0 + j], rss[0][j] + rss[1][j] + rss[2][j] + rss[3][j]);
    }
}

// ---------------------------------------------------------------------------
// lc: per-ch affine (from stats) + relu on load, 3-tap conv -> 62ch,
// fused GLOBAL stats of output
// ---------------------------------------------------------------------------
template <int POS>
__global__ __launch_bounds__(256) void k_lc(const float* __restrict__ in,
                                            const float* __restrict__ stp,
                                            const float* __restrict__ g,
                                            const float* __restrict__ be,
                                            float inv,
                                            const float* __restrict__ lcw,
                                            const float* __restrict__ lcb,
                                            float* __restrict__ out,
                                            float* __restrict__ sto) {
    __shared__ float sAff[128];
    __shared__ float sred[4], ssred[4];
    if (threadIdx.x < 64) {
        int t = threadIdx.x;
        float mm = stp[t] * inv;
        float vv = stp[64 + t] * inv - mm * mm;
        float sc = g[t] * rsqrtf(vv + EPSF);
        sAff[t] = sc;
        sAff[64 + t] = be[t] - mm * sc;
    }
    __syncthreads();
    int morig = blockIdx.x * 256 + threadIdx.x;
    bool valid = morig < Bn * POS;
    int m = valid ? morig : Bn * POS - 1;
    int b = m / POS; int p = m - b * POS;
    const float* ip = in + (size_t)b * 64 * POS + p;
    float* op = out + (size_t)b * 62 * POS + p;
    float ts = 0.f, tss = 0.f;
    float y0 = fmaxf(sAff[0] * ip[0]           + sAff[64], 0.f);
    float y1 = fmaxf(sAff[1] * ip[(size_t)POS] + sAff[65], 0.f);
    for (int c = 0; c < 62; ++c) {
        float y2 = fmaxf(sAff[c + 2] * ip[(size_t)(c + 2) * POS] + sAff[64 + c + 2], 0.f);
        float o = lcb[c] + y0 * lcw[c * 3] + y1 * lcw[c * 3 + 1] + y2 * lcw[c * 3 + 2];
        op[(size_t)c * POS] = o;
        if (valid) { ts += o; tss += o * o; }
        y0 = y1; y1 = y2;
    }
    ts = wred(ts); tss = wred(tss);
    int wv = threadIdx.x >> 6, ln = threadIdx.x & 63;
    if (ln == 0) { sred[wv] = ts; ssred[wv] = tss; }
    __syncthreads();
    if (threadIdx.x == 0) {
        atomicAdd(&sto[0],  sred[0] + sred[1] + sred[2] + sred[3]);
        atomicAdd(&sto[64], ssred[0] + ssred[1] + ssred[2] + ssred[3]);
    }
}

// ---------------------------------------------------------------------------
// mix: scalar affine+relu, channel-mix 62->64, fused per-channel stats
// ---------------------------------------------------------------------------
template <int POS>
__global__ __launch_bounds__(256) void k_mix(const float* __restrict__ in,
                                             const float* __restrict__ stp,
                                             const float* __restrict__ g,
                                             const float* __restrict__ be,
                                             float inv,
                                             const float* __restrict__ Wm,
                                             const float* __restrict__ bm,
                                             float* __restrict__ out,
                                             float* __restrict__ sto) {
    __shared__ float redS[4][64], redSS[4][64];
    float mm = stp[0] * inv;
    float vv = stp[64] * inv - mm * mm;
    float s0 = g[0] * rsqrtf(vv + EPSF);
    float t0 = be[0] - mm * s0;

    int morig = blockIdx.x * 256 + threadIdx.x;
    bool valid = morig < Bn * POS;
    int m = valid ? morig : Bn * POS - 1;
    int b = m / POS; int p = m - b * POS;
    const float* ip = in + (size_t)b * 62 * POS + p;
    float z[62];
    #pragma unroll
    for (int d = 0; d < 62; ++d)
        z[d] = fmaxf(s0 * ip[(size_t)d * POS] + t0, 0.f);
    float* op = out + (size_t)b * 64 * POS + p;
    int lane = threadIdx.x & 63, wv = threadIdx.x >> 6;
    float myS = 0.f, mySS = 0.f;
    for (int c = 0; c < 64; ++c) {
        float acc = bm[c];
        #pragma unroll
        for (int d = 0; d < 62; ++d) acc += z[d] * Wm[c * 62 + d];
        op[(size_t)c * POS] = acc;
        float vvv = valid ? acc : 0.f;
        float sT  = bfly(vvv);
        float ssT = bfly(vvv * vvv);
        if (lane == c) { myS = sT; mySS = ssT; }
    }
    redS[wv][lane] = myS; redSS[wv][lane] = mySS;
    __syncthreads();
    if (threadIdx.x < 64) {
        int t = threadIdx.x;
        atomicAdd(&sto[t],      redS[0][t] + redS[1][t] + redS[2][t] + redS[3][t]);
        atomicAdd(&sto[64 + t], redSS[0][t] + redSS[1][t] + redSS[2][t] + redSS[3][t]);
    }
}

// ---------------------------------------------------------------------------
// prep: fp32 [b][64][P] + affine(from stats) -> bf16 channel-last halves
// ---------------------------------------------------------------------------
template <int IH, int IW>
__global__ __launch_bounds__(256) void k_prep_in(const float* __restrict__ in,
                                                 const float* __restrict__ stp,
                                                 const float* __restrict__ g,
                                                 const float* __restrict__ be,
                                                 float inv,
                                                 __bf16* __restrict__ out) {
    constexpr int P = IH * IW;
    __shared__ float tile[64][65];
    const int b = blockIdx.y, p0 = blockIdx.x * 64;
    const int pl = threadIdx.x & 63, ch4 = threadIdx.x >> 6;
    #pragma unroll
    for (int i = 0; i < 16; ++i) {
        int c = i * 4 + ch4;
        int p = p0 + pl; if (p > P - 1) p = P - 1;
        tile[pl][c] = in[((size_t)b * 64 + c) * P + p];
    }
    __syncthreads();
    const int cl = threadIdx.x & 63;
    float mm = stp[cl] * inv;
    float vv = stp[64 + cl] * inv - mm * mm;
    float sc = g[cl] * rsqrtf(vv + EPSF);
    float sh = be[cl] - mm * sc;
    #pragma unroll
    for (int i = 0; i < 16; ++i) {
        int plocal = i * 4 + ch4;
        int p = p0 + plocal; if (p > P - 1) p = P - 1;
        int ih = p / IW, iw = p - ih * IW;
        float v = sc * tile[plocal][cl] + sh;
        out[(((size_t)b * IH + ih) * 2 + (cl >> 5)) * (IW * 32) + iw * 32 + (cl & 31)] = (__bf16)v;
    }
}

// weights -> bf16 packed [pos][c(4)][sub(2)][oc(64)][j(8)]
template <int KH, int KW>
__global__ __launch_bounds__(256) void k_prep_w(const float* __restrict__ w,
                                                __bf16* __restrict__ wq) {
    int idx = blockIdx.x * 256 + threadIdx.x;
    constexpr int TOT = KH * KW * 4096;
    if (idx >= TOT) return;
    int j   = idx & 7;
    int oc  = (idx >> 3) & 63;
    int sub = (idx >> 9) & 1;
    int c   = (idx >> 10) & 3;
    int pos = idx >> 12;
    int kh = pos / KW, kw = pos - kh * KW;
    int ic = c * 16 + sub * 8 + j;
    wq[idx] = (__bf16)w[(((size_t)oc * 64 + ic) * KH + kh) * KW + kw];
}

// ---------------------------------------------------------------------------
// implicit-GEMM conv, bf16 MFMA 32x32x16, XOR-swizzled LDS, fused ch-stats
// ---------------------------------------------------------------------------
template <int KH, int KW, int IH, int IW, int OH, int OW, int NR>
__global__ __launch_bounds__(256, 3) void k_convmfma(
    const __bf16* __restrict__ in,
    const __bf16* __restrict__ wq,
    const float* __restrict__ bias,
    float* __restrict__ out,
    float* __restrict__ sto)
{
    constexpr int P = OH * OW;
    const int b  = blockIdx.y;
    const int m0 = blockIdx.x * 256;
    const int t  = threadIdx.x;
    const int lane = t & 63;
    const int wv = t >> 6;
    const int l31 = lane & 31, lh = lane >> 5;

    __shared__ __align__(16) __bf16 As[NR * IW * 32 + 64];

    const int oh_lo = m0 / OW;
    int posm[2];
    #pragma unroll
    for (int mt = 0; mt < 2; ++mt) {
        int m = m0 + wv * 64 + mt * 32 + l31;
        int mc = m > P - 1 ? P - 1 : m;
        int oh = mc / OW, ow = mc - oh * OW;
        posm[mt] = (oh - oh_lo) * IW + ow;
    }

    ffrag acc[2][2] = {};

    for (int ich = 0; ich < 2; ++ich) {
        __syncthreads();
        constexpr int ROWCH = IW * 4;          // 16B chunks per row-half
        constexpr int CH = NR * ROWCH;
        for (int idx = t; idx < CH; idx += 256) {
            int r = idx / ROWCH, o = idx - r * ROWCH;
            int ih = oh_lo + r; if (ih > IH - 1) ih = IH - 1;
            const __bf16* src = in + ((size_t)(b * IH + ih) * 2 + ich) * (IW * 32) + o * 8;
            int sw = idx ^ ((idx >> 2) & 7);
            *(uint4*)&As[sw * 8] = *(const uint4*)src;
        }
        __syncthreads();

        const __bf16* wich = wq + ich * 2048;
        for (int kh = 0; kh < KH; ++kh) {
            const int rowoff = kh * IW;
            const __bf16* wkh = wich + (size_t)(kh * KW) * 4096 + lh * 512 + l31 * 8;
            #pragma unroll 2
            for (int kw = 0; kw < KW; ++kw) {
                const __bf16* wp = wkh + kw * 4096;
                #pragma unroll
                for (int cc = 0; cc < 2; ++cc) {
                    int X0 = posm[0] + rowoff + kw;
                    int X1 = posm[1] + rowoff + kw;
                    int gc0 = (X0 << 2) + cc * 2 + lh;
                    int gc1 = (X1 << 2) + cc * 2 + lh;
                    bfrag a0 = *(const bfrag*)&As[(gc0 ^ (X0 & 7)) * 8];
                    bfrag a1 = *(const bfrag*)&As[(gc1 ^ (X1 & 7)) * 8];
                    bfrag b0 = *(const bfrag*)(wp + cc * 1024);
                    bfrag b1 = *(const bfrag*)(wp + cc * 1024 + 256);
                    acc[0][0] = __builtin_amdgcn_mfma_f32_32x32x16_bf16(a0, b0, acc[0][0], 0, 0, 0);
                    acc[0][1] = __builtin_amdgcn_mfma_f32_32x32x16_bf16(a0, b1, acc[0][1], 0, 0, 0);
                    acc[1][0] = __builtin_amdgcn_mfma_f32_32x32x16_bf16(a1, b0, acc[1][0], 0, 0, 0);
                    acc[1][1] = __builtin_amdgcn_mfma_f32_32x32x16_bf16(a1, b1, acc[1][1], 0, 0, 0);
                }
            }
        }
    }

    // epilogue: C/D col = l31, row = (reg&3) + 8*(reg>>2) + 4*lh; fused stats
    float sS[2] = {0.f, 0.f}, sSS[2] = {0.f, 0.f};
    #pragma unroll
    for (int nt = 0; nt < 2; ++nt) {
        int oc = nt * 32 + l31;
        float bv = bias[oc];
        float* op = out + ((size_t)b * 64 + oc) * P;
        #pragma unroll
        for (int mt = 0; mt < 2; ++mt) {
            int mbase = m0 + wv * 64 + mt * 32 + lh * 4;
            #pragma unroll
            for (int g = 0; g < 4; ++g) {
                int mr = mbase + g * 8;
                if (mr < P) {
                    float v0 = acc[mt][nt][g * 4 + 0] + bv;
                    float v1 = acc[mt][nt][g * 4 + 1] + bv;
                    *(float2*)(op + mr) = make_float2(v0, v1);
                    sS[nt] += v0 + v1; sSS[nt] += v0 * v0 + v1 * v1;
                    if (mr + 2 < P) {
                        float v2 = acc[mt][nt][g * 4 + 2] + bv;
                        float v3 = acc[mt][nt][g * 4 + 3] + bv;
                        *(float2*)(op + mr + 2) = make_float2(v2, v3);
                        sS[nt] += v2 + v3; sSS[nt] += v2 * v2 + v3 * v3;
                    }
                }
            }
        }
    }
    #pragma unroll
    for (int nt = 0; nt < 2; ++nt) {
        sS[nt]  += __shfl_down(sS[nt], 32);
        sSS[nt] += __shfl_down(sSS[nt], 32);
    }
    __syncthreads();
    float* redS  = (float*)As;        // 256 floats
    float* redSS = redS + 256;        // 256 floats
    if (lane < 32) {
        #pragma unroll
        for (int nt = 0; nt < 2; ++nt) {
            redS[wv * 64 + nt * 32 + l31]  = sS[nt];
            redSS[wv * 64 + nt * 32 + l31] = sSS[nt];
        }
    }
    __syncthreads();
    if (t < 64) {
        float s  = redS[t]  + redS[64 + t]  + redS[128 + t]  + redS[192 + t];
        float ss = redSS[t] + redSS[64 + t] + redSS[128 + t] + redSS[192 + t];
        atomicAdd(&sto[t], s);
        atomicAdd(&sto[64 + t], ss);
    }
}

// ---------------------------------------------------------------------------
// FC head
// ---------------------------------------------------------------------------
__global__ __launch_bounds__(256) void k_transpose(const float* __restrict__ in,
                                                   const float* __restrict__ stp,
                                                   const float* __restrict__ g,
                                                   const float* __restrict__ be,
                                                   float inv,
                                                   float* __restrict__ hT) {
    __shared__ float tile[32][33];
    int j0 = blockIdx.x * 32, b0 = blockIdx.y * 32;
    int lo = threadIdx.x & 31, hi = threadIdx.x >> 5;
    int c  = (j0 + lo) / P3;
    float mm = stp[c] * inv;
    float vv = stp[64 + c] * inv - mm * mm;
    float sc = g[c] * rsqrtf(vv + EPSF);
    float sh = be[c] - mm * sc;
    #pragma unroll
    for (int tt = 0; tt < 4; ++tt) {
        int bl = tt * 8 + hi;
        tile[bl][lo] = sc * in[(size_t)(b0 + bl) * KFC + (j0 + lo)] + sh;
    }
    __syncthreads();
    #pragma unroll
    for (int tt = 0; tt < 4; ++tt) {
        int jl = tt * 8 + hi;
        hT[(size_t)(j0 + jl) * Bn + b0 + lo] = tile[lo][jl];
    }
}

__global__ __launch_bounds__(256) void k_fc1(const float* __restrict__ hT,
                                             const float* __restrict__ Wf1,
                                             float* __restrict__ Pb) {
    int lane = threadIdx.x & 63;
    int f0 = __builtin_amdgcn_readfirstlane((threadIdx.x >> 6) * 16);
    int b  = blockIdx.y * 64 + lane;
    int kc = blockIdx.x;
    int k0 = kc * FCKL;
    float acc[16] = {};
    for (int k = k0; k < k0 + FCKL; ++k) {
        float hv = hT[(size_t)k * Bn + b];
        #pragma unroll
        for (int f = 0; f < 16; ++f)
            acc[f] += hv * Wf1[(size_t)(f0 + f) * KFC + k];
    }
    float* pp = Pb + (size_t)kc * 8192 + (size_t)b * 64 + f0;
    #pragma unroll
    for (int f = 0; f < 16; ++f) pp[f] = acc[f];
}

__global__ __launch_bounds__(256) void k_fc1red(const float* __restrict__ Pb,
                                                float* __restrict__ F) {
    int m = blockIdx.x * 256 + threadIdx.x;
    float s = 0.f;
    for (int kc = 0; kc < FCCH; ++kc) s += Pb[(size_t)kc * 8192 + m];
    F[m] = s;
}

__global__ void k_fcstats(const float* __restrict__ F, const float* __restrict__ bf1,
                          const float* __restrict__ gf, const float* __restrict__ bef,
                          float* __restrict__ fa) {
    int f = threadIdx.x;
    float s = 0.f, ss = 0.f;
    for (int b = 0; b < Bn; ++b) {
        float v = F[b * 64 + f] + bf1[f];
        s += v; ss += v * v;
    }
    float m  = s / 128.f;
    float va = ss / 128.f - m * m;
    float sc = gf[f] * rsqrtf(va + EPSF);
    fa[f] = sc;
    fa[64 + f] = bef[f] - m * sc;
}

__global__ __launch_bounds__(256) void k_fc2(const float* __restrict__ F,
                                             const float* __restrict__ bf1,
                                             const float* __restrict__ fa,
                                             const float* __restrict__ Wf2,
                                             const float* __restrict__ bf2,
                                             float* __restrict__ out) {
    int m = blockIdx.x * 256 + threadIdx.x;
    if (m >= Bn * 35) return;
    int b = m / 35, o = m - b * 35;
    float acc = bf2[o];
    for (int f = 0; f < 64; ++f) {
        float v = F[b * 64 + f] + bf1[f];
        float z = fmaxf(fa[f] * v + fa[64 + f], 0.f);
        acc += z * Wf2[o * 64 + f];
    }
    out[m] = acc;
}

// ---------------------------------------------------------------------------
// launch
// ---------------------------------------------------------------------------
extern "C" void kernel_launch(void* const* d_in, const int* in_sizes, int n_in,
                              void* d_out, int out_size, void* d_ws, size_t ws_size,
                              hipStream_t stream) {
    const float* x    = (const float*)d_in[0];
    const float* W11  = (const float*)d_in[1];
    const float* b11  = (const float*)d_in[2];
    const float* g11  = (const float*)d_in[3];
    const float* be11 = (const float*)d_in[4];
    const float* lc1w = (const float*)d_in[5];
    const float* lc1b = (const float*)d_in[6];
    const float* g12  = (const float*)d_in[7];
    const float* be12 = (const float*)d_in[8];
    const float* W13  = (const float*)d_in[9];
    const float* b13  = (const float*)d_in[10];
    const float* g13  = (const float*)d_in[11];
    const float* be13 = (const float*)d_in[12];
    const float* W21  = (const float*)d_in[13];
    const float* b21  = (const float*)d_in[14];
    const float* g21  = (const float*)d_in[15];
    const float* be21 = (const float*)d_in[16];
    const float* lc2w = (const float*)d_in[17];
    const float* lc2b = (const float*)d_in[18];
    const float* g22  = (const float*)d_in[19];
    const float* be22 = (const float*)d_in[20];
    const float* W23  = (const float*)d_in[21];
    const float* b23  = (const float*)d_in[22];
    const float* g23  = (const float*)d_in[23];
    const float* be23 = (const float*)d_in[24];
    const float* W31  = (const float*)d_in[25];
    const float* b31  = (const float*)d_in[26];
    const float* g31  = (const float*)d_in[27];
    const float* be31 = (const float*)d_in[28];
    const float* lc3w = (const float*)d_in[29];
    const float* lc3b = (const float*)d_in[30];
    const float* g32  = (const float*)d_in[31];
    const float* be32 = (const float*)d_in[32];
    const float* W33  = (const float*)d_in[33];
    const float* b33  = (const float*)d_in[34];
    const float* g33  = (const float*)d_in[35];
    const float* be33 = (const float*)d_in[36];
    const float* Wf1  = (const float*)d_in[37];
    const float* bf1  = (const float*)d_in[38];
    const float* gf   = (const float*)d_in[39];
    const float* bef  = (const float*)d_in[40];
    const float* Wf2  = (const float*)d_in[41];
    const float* bf2  = (const float*)d_in[42];

    float* ws  = (float*)d_ws;
    float* A   = ws + oA;
    float* Bb  = ws + oB;
    __bf16* Bcl = (__bf16*)(ws + oB);
    __bf16* wq2 = (__bf16*)(ws + oW2);
    __bf16* wq3 = (__bf16*)(ws + oW3);
    float* Pb  = ws + oP;
    float* st  = ws + oSt;
    float* F   = ws + oF;
    float* fca = ws + oFA;

    hipMemsetAsync(st, 0, 9 * 128 * sizeof(float), stream);

    const int blk1 = (M1 + 255) / 256;
    const int blk2 = M2 / 256;
    const int blk3 = M3 / 256;

    k_prep_w<KH2, KW2><<<(KH2 * KW2 * 4096 + 255) / 256, 256, 0, stream>>>(W21, wq2);
    k_prep_w<KH3, KW3><<<(KH3 * KW3 * 4096 + 255) / 256, 256, 0, stream>>>(W31, wq3);

    // ---- stage 1 ----
    k_conv1<<<dim3(blk1, 8), 256, 0, stream>>>(x, W11, b11, A, st + 0 * 128);
    k_lc<P1><<<blk1, 256, 0, stream>>>(A, st + 0 * 128, g11, be11, 1.0f / (float)M1,
                                       lc1w, lc1b, Bb, st + 1 * 128);
    k_mix<P1><<<blk1, 256, 0, stream>>>(Bb, st + 1 * 128, g12, be12, 1.0f / (62.0f * (float)M1),
                                        W13, b13, A, st + 2 * 128);

    // ---- stage 2 ----
    k_prep_in<H1, Wo1><<<dim3((P1 + 63) / 64, Bn), 256, 0, stream>>>(
        A, st + 2 * 128, g13, be13, 1.0f / (float)M1, Bcl);
    k_convmfma<KH2, KW2, H1, Wo1, H2, Wo2, 25>
        <<<dim3((P2 + 255) / 256, Bn), 256, 0, stream>>>(Bcl, wq2, b21, A, st + 3 * 128);
    k_lc<P2><<<blk2, 256, 0, stream>>>(A, st + 3 * 128, g21, be21, 1.0f / (float)M2,
                                       lc2w, lc2b, Bb, st + 4 * 128);
    k_mix<P2><<<blk2, 256, 0, stream>>>(Bb, st + 4 * 128, g22, be22, 1.0f / (62.0f * (float)M2),
                                        W23, b23, A, st + 5 * 128);

    // ---- stage 3 ----
    k_prep_in<H2, Wo2><<<dim3((P2 + 63) / 64, Bn), 256, 0, stream>>>(
        A, st + 5 * 128, g23, be23, 1.0f / (float)M2, Bcl);
    k_convmfma<KH3, KW3, H2, Wo2, H3, Wo3, 24>
        <<<dim3((P3 + 255) / 256, Bn), 256, 0, stream>>>(Bcl, wq3, b31, A, st + 6 * 128);
    k_lc<P3><<<blk3, 256, 0, stream>>>(A, st + 6 * 128, g31, be31, 1.0f / (float)M3,
                                       lc3w, lc3b, Bb, st + 7 * 128);
    k_mix<P3><<<blk3, 256, 0, stream>>>(Bb, st + 7 * 128, g32, be32, 1.0f / (62.0f * (float)M3),
                                        W33, b33, A, st + 8 * 128);

    // ---- FC head ----
    k_transpose<<<dim3(KFC / 32, Bn / 32), 256, 0, stream>>>(
        A, st + 8 * 128, g33, be33, 1.0f / (float)M3, Bb);
    k_fc1<<<dim3(FCCH, 2), 256, 0, stream>>>(Bb, Wf1, Pb);
    k_fc1red<<<32, 256, 0, stream>>>(Pb, F);
    k_fcstats<<<1, 64, 0, stream>>>(F, bf1, gf, bef, fca);
    k_fc2<<<(Bn * 35 + 255) / 256, 256, 0, stream>>>(F, bf1, fca, Wf2, bf2, (float*)d_out);
}